// Round 3
// baseline (374.215 us; speedup 1.0000x reference)
//
#include <hip/hip_runtime.h>

#define PS 32
#define NPIX (PS * PS)
#define NB 36
#define WPB 4      // waves (patches) per block
#define FCAP 64    // deferred-fixup list capacity per wave

// ---------------------------------------------------------------------------
// Init kernel: gk10[p] = float32(10 * CircularGaussKernel(32)) computed in f64,
// replicating numpy linspace + exp + normalize semantics, then cast to f32.
// ---------------------------------------------------------------------------
__global__ __launch_bounds__(256) void gk_init_kernel(float* __restrict__ gk10) {
    __shared__ double red[256];
    const int tid = threadIdx.x;
    const double delta = 32.0 / 31.0;       // numpy linspace step, f64
    const double sigma2 = 0.9 * 256.0;      // 0.9 * half^2, f64

    double kv[4];
    double s = 0.0;
#pragma unroll
    for (int j = 0; j < 4; ++j) {
        int p = tid * 4 + j;
        int r = p >> 5, c = p & 31;
        double xr = (r == 31) ? 16.0 : ((double)r * delta + (-16.0));
        double xc = (c == 31) ? 16.0 : ((double)c * delta + (-16.0));
        double d2 = xc * xc + xr * xr;
        kv[j] = exp(-d2 / sigma2);
        s += kv[j];
    }
    red[tid] = s;
    __syncthreads();
    for (int off = 128; off > 0; off >>= 1) {
        if (tid < off) red[tid] += red[tid + off];
        __syncthreads();
    }
    double sum = red[0];
#pragma unroll
    for (int j = 0; j < 4; ++j) {
        int p = tid * 4 + j;
        gk10[p] = __fmul_rn(10.0f, (float)(kv[j] / sum));
    }
}

// ---------------------------------------------------------------------------
// Main kernel: 4 waves per block, ONE WAVE PER PATCH. No __syncthreads.
// Hot loop is branch-free f32; rare bin-boundary pixels are deferred to a
// single f64 fixup pass after the loop (keeps the hot code compact).
// ---------------------------------------------------------------------------
__global__ __launch_bounds__(256) void orient_kernel(const float* __restrict__ x,
                                                     const float* __restrict__ gk10,
                                                     float* __restrict__ out) {
    const float PI_F    = 3.14159265358979323846f;   // 0x40490FDB
    const float TWOPI_F = 6.28318530717958647692f;   // 0x40C90FDB

    __shared__ __align__(16) float tile[WPB][NPIX];
    __shared__ float hist[WPB][NB];
    __shared__ int   nflag[WPB];
    __shared__ int   flagp[WPB][FCAP];

    const int tid = threadIdx.x;
    const int w = tid >> 6;          // wave id within block
    const int l = tid & 63;          // lane within wave
    const int patch = blockIdx.x * WPB + w;

    float* tw = tile[w];
    float* hw = hist[w];

    // ---- Issue all global loads up front (patch + gaussian weights)
    const float4* src = reinterpret_cast<const float4*>(x + (size_t)patch * NPIX);
    float4 ld[4];    // lane's own 4 float4 groups (these ARE the "self" quads)
    float4 gkq[4];
#pragma unroll
    for (int k = 0; k < 4; ++k) ld[k] = src[k * 64 + l];
    {
        const int r  = l >> 3;
        const int c0 = (l & 7) << 2;
#pragma unroll
        for (int k = 0; k < 4; ++k)
            gkq[k] = *reinterpret_cast<const float4*>(&gk10[(k * 8 + r) * PS + c0]);
    }

    // ---- Stage patch into LDS; init hist + flag counter
    float4* dst = reinterpret_cast<float4*>(tw);
#pragma unroll
    for (int k = 0; k < 4; ++k) dst[k * 64 + l] = ld[k];
    if (l < NB) hw[l] = 0.0f;
    if (l == 0) nflag[w] = 0;
    asm volatile("s_waitcnt lgkmcnt(0)" ::: "memory");

    // ---- Batch ALL neighbor reads into register arrays (issue early, use late)
    const int r  = l >> 3;           // row 0..31 within each 8-row band
    const int c0 = (l & 7) << 2;     // col 0,4,...,28
    float4 up[4], dn[4];
    float  lsc[4], rsc[4];
#pragma unroll
    for (int k = 0; k < 4; ++k) {
        const int row = k * 8 + r;
        const int rowOff = row << 5;
        const int upOff  = ((row == 0)  ? 0  : (row - 1)) << 5;   // replicate pad
        const int dnOff  = ((row == 31) ? 31 : (row + 1)) << 5;
        up[k]  = *reinterpret_cast<const float4*>(&tw[upOff + c0]);
        dn[k]  = *reinterpret_cast<const float4*>(&tw[dnOff + c0]);
        lsc[k] = tw[rowOff + ((c0 == 0) ? 0 : (c0 - 1))];
        rsc[k] = tw[rowOff + ((c0 + 4 > 31) ? 31 : (c0 + 4))];
    }

    // ---- Hot loop: 16 pixels/lane, branch-free except the rare flag push
#pragma unroll
    for (int k = 0; k < 4; ++k) {
        const int rowBase = (k * 8 + r) << 5;
        float sv[4]  = {ld[k].x, ld[k].y, ld[k].z, ld[k].w};
        float uv[4]  = {up[k].x, up[k].y, up[k].z, up[k].w};
        float dv[4]  = {dn[k].x, dn[k].y, dn[k].z, dn[k].w};
        float gk4[4] = {gkq[k].x, gkq[k].y, gkq[k].z, gkq[k].w};
        float lv[4]  = {lsc[k], sv[0], sv[1], sv[2]};
        float rv[4]  = {sv[1],  sv[2], sv[3], rsc[k]};

#pragma unroll
        for (int j = 0; j < 4; ++j) {
            // Reference f32 op order for magnitude (no contraction):
            float gx = __fmul_rn(0.5f, __fsub_rn(lv[j], rv[j]));
            float gy = __fmul_rn(0.5f, __fsub_rn(uv[j], dv[j]));
            float s2 = __fadd_rn(__fadd_rn(__fmul_rn(gx, gx), __fmul_rn(gy, gy)), 1e-10f);
            float mag = __fmul_rn(__fsqrt_rn(s2), gk4[j]);

            // Fast atan2 directly in bin units: obig = (atan2+pi)*36/(2pi)
            float ax = fabsf(gx), ay = fabsf(gy);
            float mn = fminf(ax, ay), mx = fmaxf(ax, ay);
            float rr = mn * __builtin_amdgcn_rcpf(mx);   // ~1 ulp
            float t  = rr * rr;
            float u = 0.00282363896258175373077393f;     // SLEEF deg-17 odd minimax
            u = fmaf(u, t, -0.0159569028764963150024414f);
            u = fmaf(u, t,  0.0425049886107444763183594f);
            u = fmaf(u, t, -0.0748900920152664184570312f);
            u = fmaf(u, t,  0.106347933411598205566406f);
            u = fmaf(u, t, -0.142027363181114196777344f);
            u = fmaf(u, t,  0.199926957488059997558594f);
            u = fmaf(u, t, -0.333331018686294555664062f);
            float at = fmaf(rr * t, u, rr);              // atan(rr), [0, pi/4]
            float A  = at * 5.72957795130823208768f;     // -> bin units [0, 4.5]
            A = (mx > 0.0f) ? A : 0.0f;                  // atan2(0,0) = 0
            float q = (ay > ax) ? (9.0f - A) : A;
            q = (gx < 0.0f) ? (18.0f - q) : q;
            q = (gy < 0.0f) ? (0.0f - q) : q;
            float obig = q + 18.0f;                      // [0, 36]
            float bo0f = floorf(obig);
            float wo1  = __fsub_rn(obig, bo0f);

            // Boundary pixels: defer to exact f64 fixup (skip the atomic here)
            bool bad = (wo1 < 2e-5f) | (wo1 > 1.0f - 2e-5f);
            if (!bad) {
                int bo = (int)bo0f;
                if (bo >= NB) bo -= NB;
                float wo0 = __fmul_rn(__fsub_rn(1.0f, wo1), mag);
                atomicAdd(&hw[bo], wo0);
            } else {
                int idx = atomicAdd(&nflag[w], 1);
                if (idx < FCAP) flagp[w][idx] = rowBase + c0 + j;
            }
        }
    }
    asm volatile("s_waitcnt lgkmcnt(0)" ::: "memory");

    // ---- Exact f64 fixup for flagged pixels (~0.04 expected per patch).
    // ONE copy of the f64 atan2 code, outside the hot loop.
    int nf = nflag[w];
    if (nf > FCAP) nf = FCAP;
    for (int s = l; s < nf; s += 64) {
        int p = flagp[w][s];
        int rr2 = p >> 5, cc = p & 31;
        float cl = tw[p - (cc > 0 ? 1 : 0)];
        float cr = tw[p + (cc < 31 ? 1 : 0)];
        float cu = tw[p - (rr2 > 0 ? 32 : 0)];
        float cd = tw[p + (rr2 < 31 ? 32 : 0)];
        float gx = __fmul_rn(0.5f, __fsub_rn(cl, cr));
        float gy = __fmul_rn(0.5f, __fsub_rn(cu, cd));
        float s2 = __fadd_rn(__fadd_rn(__fmul_rn(gx, gx), __fmul_rn(gy, gy)), 1e-10f);
        float mag = __fmul_rn(__fsqrt_rn(s2), gk10[p]);

        float ori  = (float)atan2((double)gy, (double)gx);  // correctly-rounded f32
        float obig = __fdiv_rn(__fmul_rn(36.0f, __fadd_rn(ori, PI_F)), TWOPI_F);
        float bo0f = floorf(obig);
        float wo1  = __fsub_rn(obig, bo0f);
        int bo = (int)bo0f;
        if (bo >= NB) bo -= NB;
        float wo0 = __fmul_rn(__fsub_rn(1.0f, wo1), mag);
        atomicAdd(&hw[bo], wo0);
    }
    asm volatile("s_waitcnt lgkmcnt(0)" ::: "memory");

    // ---- Smoothing (lanes 0..35): sm = 0.33*h[i-1] + 0.34*h[i] + 0.33*h[i+1]
    float sm = 0.0f;
    if (l < NB) {
        const float inv = 1.0f / 1024.0f;  // exact power of 2
        float hm = (l > 0)      ? __fmul_rn(hw[l - 1], inv) : 0.0f;
        float h0 =                __fmul_rn(hw[l],     inv);
        float hp = (l < NB - 1) ? __fmul_rn(hw[l + 1], inv) : 0.0f;
        sm = __fadd_rn(__fadd_rn(__fmul_rn(0.33f, hm), __fmul_rn(0.34f, h0)),
                       __fmul_rn(0.33f, hp));
    }

    // ---- First-wins argmax via packed-key butterfly reduce.
    // sm >= 0 always, so IEEE bits are monotonic; tie -> smaller index wins.
    unsigned long long key =
        (l < NB) ? ((((unsigned long long)__float_as_uint(sm)) << 6) |
                    (unsigned long long)(63 - l))
                 : 0ull;
#pragma unroll
    for (int off = 32; off > 0; off >>= 1) {
        unsigned long long o = __shfl_xor(key, off, 64);
        key = (o > key) ? o : key;
    }

    if (l == 0) {
        int bi = 63 - (int)(key & 63);
        float t2 = __fdiv_rn(__fmul_rn(TWOPI_F, (float)bi), 36.0f);
        out[patch] = __fsub_rn(PI_F, t2);
    }
}

extern "C" void kernel_launch(void* const* d_in, const int* in_sizes, int n_in,
                              void* d_out, int out_size, void* d_ws, size_t ws_size,
                              hipStream_t stream) {
    const float* x = (const float*)d_in[0];
    float* out = (float*)d_out;
    float* gk10 = (float*)d_ws;   // 1024 floats = 4 KB scratch

    const int B = in_sizes[0] / NPIX;

    gk_init_kernel<<<1, 256, 0, stream>>>(gk10);
    orient_kernel<<<B / WPB, 256, 0, stream>>>(x, gk10, out);
}